// Round 1
// baseline (128.503 us; speedup 1.0000x reference)
//
#include <hip/hip_runtime.h>
#include <stdint.h>

#define T_TOK 8192
#define DIMK 1024
#define NEXP 8
#define BM 128
#define BN 128
#define BK 64
#define MAXROWS (T_TOK + NEXP * BM)   /* 9216 gathered rows incl. padding */
#define MAXTILES (T_TOK / BM + NEXP)  /* 72 row tiles worst case */

typedef __attribute__((ext_vector_type(4))) float f32x4;
typedef __attribute__((ext_vector_type(8))) short short8;
typedef __attribute__((ext_vector_type(4))) unsigned short us4;

__device__ __forceinline__ unsigned short f2bf(float f) {
  uint32_t u = __builtin_bit_cast(uint32_t, f);
  u += 0x7FFFu + ((u >> 16) & 1u);   // RTNE
  return (unsigned short)(u >> 16);
}

__device__ __forceinline__ void gload_lds16(const void* g, void* l) {
  __builtin_amdgcn_global_load_lds(
      (const __attribute__((address_space(1))) void*)g,
      (__attribute__((address_space(3))) void*)l, 16, 0, 0);
}

// ---- expert bucketing -------------------------------------------------------
__global__ void k_count(const int* __restrict__ idx, int* __restrict__ hdr) {
  int t = blockIdx.x * 256 + threadIdx.x;
  atomicAdd(&hdr[idx[t]], 1);
}

__global__ void k_offsets(int* hdr) {
  // hdr[0..7] = counts; hdr[8..15] = cursors (set to padded segment starts)
  if (threadIdx.x == 0) {
    int off = 0;
    for (int e = 0; e < NEXP; e++) {
      hdr[8 + e] = off;
      off += ((hdr[e] + BM - 1) >> 7) << 7;
    }
  }
}

__global__ void k_assign(const int* __restrict__ idx, int* __restrict__ hdr,
                         int* __restrict__ row2tok) {
  int t = blockIdx.x * 256 + threadIdx.x;
  int e = idx[t];
  int pos = atomicAdd(&hdr[8 + e], 1);
  row2tok[pos] = t;
}

// ---- dtype conversion / gather ---------------------------------------------
__global__ void k_wconv(const float* __restrict__ W, unsigned short* __restrict__ Wb) {
  int i = (blockIdx.x * 256 + threadIdx.x) * 4;
  f32x4 v = *(const f32x4*)(W + i);
  us4 o;
  o[0] = f2bf(v[0]); o[1] = f2bf(v[1]); o[2] = f2bf(v[2]); o[3] = f2bf(v[3]);
  *(us4*)(Wb + i) = o;
}

__global__ void k_gather(const float* __restrict__ X, const int* __restrict__ row2tok,
                         unsigned short* __restrict__ Xg) {
  int r = blockIdx.x;
  int t = row2tok[r];
  int d = threadIdx.x * 4;
  us4 o = {0, 0, 0, 0};
  if (t >= 0) {
    f32x4 v = *(const f32x4*)(X + (size_t)t * DIMK + d);
    o[0] = f2bf(v[0]); o[1] = f2bf(v[1]); o[2] = f2bf(v[2]); o[3] = f2bf(v[3]);
  }
  *(us4*)(Xg + (size_t)r * DIMK + d) = o;
}

// ---- grouped GEMM: C[row] = Xg[row] . Wb[e]^T ------------------------------
__global__ __launch_bounds__(256, 2) void k_gemm(
    const unsigned short* __restrict__ Xg, const unsigned short* __restrict__ Wb,
    const int* __restrict__ hdr, const int* __restrict__ row2tok,
    float* __restrict__ out) {
  __shared__ unsigned short A_lds[BM * BK];  // 16 KB
  __shared__ unsigned short B_lds[BN * BK];  // 16 KB

  // map blockIdx.x -> (expert, gathered row0) over padded segments
  int tile = blockIdx.x;
  int e = -1, row0 = 0, off = 0;
  for (int i = 0; i < NEXP; i++) {
    int te = (hdr[i] + BM - 1) >> 7;  // tiles for expert i
    if (e < 0) {
      if (tile < te) { e = i; row0 = off + tile * BM; }
      else tile -= te;
    }
    off += te << 7;
  }
  if (e < 0) return;

  const int tid = threadIdx.x;
  const int lane = tid & 63;
  const int wid = tid >> 6;
  const int wr = wid >> 1, wc = wid & 1;
  const int n0 = blockIdx.y * BN;

  // staging constants: lane covers 16B at LDS linear (chunk*1024 + lane*16)
  // LDS row = chunk*8 + (lane>>3); read side swizzles col by (row&7)<<4, so
  // the *source* column must carry the same XOR (both-sides-or-neither).
  const int st_r = lane >> 3;                        // row within 8-row chunk
  const int st_cb = ((lane & 7) ^ st_r) << 4;        // pre-swizzled byte col

  const char* a_base = (const char*)Xg + (size_t)row0 * (DIMK * 2);
  const char* b_base = (const char*)Wb + ((size_t)e * DIMK * DIMK + (size_t)n0 * DIMK) * 2;

  f32x4 acc[4][4];
  const f32x4 fzero = {0.f, 0.f, 0.f, 0.f};
#pragma unroll
  for (int m = 0; m < 4; m++)
#pragma unroll
    for (int n = 0; n < 4; n++) acc[m][n] = fzero;

  const int rsel = lane & 15;
  const int swz_r = (lane & 7) << 4;         // (row&7)<<4 for fragment rows
  const int kgrp = (lane >> 4) << 4;         // k-group byte offset (8 bf16)

  int a_row_b[4], b_row_b[4];
#pragma unroll
  for (int m = 0; m < 4; m++) a_row_b[m] = (wr * 64 + m * 16 + rsel) * (BK * 2);
#pragma unroll
  for (int n = 0; n < 4; n++) b_row_b[n] = (wc * 64 + n * 16 + rsel) * (BK * 2);

  for (int kt = 0; kt < DIMK / BK; kt++) {
    const int k0b = kt * BK * 2;
    // stage A (128x64) + B (128x64): 16 chunks of 1KB each, 4 per wave
#pragma unroll
    for (int j = 0; j < 4; j++) {
      int c = wid * 4 + j;
      int r = c * 8 + st_r;
      gload_lds16(a_base + (size_t)r * (DIMK * 2) + k0b + st_cb, (char*)A_lds + c * 1024);
      gload_lds16(b_base + (size_t)r * (DIMK * 2) + k0b + st_cb, (char*)B_lds + c * 1024);
    }
    __syncthreads();
#pragma unroll
    for (int ks = 0; ks < 2; ks++) {
      const int kb = ks * 64 + kgrp;
      short8 av[4], bv[4];
#pragma unroll
      for (int m = 0; m < 4; m++)
        av[m] = *(const short8*)((const char*)A_lds + a_row_b[m] + (kb ^ swz_r));
#pragma unroll
      for (int n = 0; n < 4; n++)
        bv[n] = *(const short8*)((const char*)B_lds + b_row_b[n] + (kb ^ swz_r));
#pragma unroll
      for (int m = 0; m < 4; m++)
#pragma unroll
        for (int n = 0; n < 4; n++)
          acc[m][n] = __builtin_amdgcn_mfma_f32_16x16x32_bf16(av[m], bv[n], acc[m][n], 0, 0, 0);
    }
    __syncthreads();
  }

  // epilogue: scatter rows back to tokens; pad rows have row2tok == -1
  const int rg4 = (lane >> 4) * 4;
#pragma unroll
  for (int m = 0; m < 4; m++) {
#pragma unroll
    for (int i = 0; i < 4; i++) {
      int rg = row0 + wr * 64 + m * 16 + rg4 + i;
      int tok = row2tok[rg];
      if (tok >= 0) {
        float* po = out + (size_t)tok * DIMK + n0 + wc * 64 + rsel;
#pragma unroll
        for (int n = 0; n < 4; n++) po[n * 16] = acc[m][n][i];
      }
    }
  }
}

extern "C" void kernel_launch(void* const* d_in, const int* in_sizes, int n_in,
                              void* d_out, int out_size, void* d_ws, size_t ws_size,
                              hipStream_t stream) {
  const float* X = (const float*)d_in[0];
  const float* W = (const float*)d_in[1];
  const int* idx = (const int*)d_in[2];
  float* out = (float*)d_out;
  char* ws = (char*)d_ws;

  int* hdr = (int*)ws;                                     // 64 ints
  int* row2tok = (int*)(ws + 256);                         // 9216 ints
  unsigned short* Wb = (unsigned short*)(ws + 65536);      // 16 MiB bf16 W
  unsigned short* Xg = (unsigned short*)(ws + 65536 + 16777216);  // 18 MiB bf16 gathered X

  hipMemsetAsync(hdr, 0, 64, stream);                       // counts + cursors = 0
  hipMemsetAsync(row2tok, 0xFF, MAXROWS * sizeof(int), stream);  // -1 pad markers

  k_count<<<T_TOK / 256, 256, 0, stream>>>(idx, hdr);
  k_offsets<<<1, 64, 0, stream>>>(hdr);
  k_assign<<<T_TOK / 256, 256, 0, stream>>>(idx, hdr, row2tok);
  k_wconv<<<(NEXP * DIMK * DIMK) / (256 * 4), 256, 0, stream>>>(W, Wb);
  k_gather<<<MAXROWS, 256, 0, stream>>>(X, row2tok, Xg);

  dim3 g(MAXTILES, DIMK / BN);
  k_gemm<<<g, 256, 0, stream>>>(Xg, Wb, hdr, row2tok, out);
}

// Round 2
// 127.107 us; speedup vs baseline: 1.0110x; 1.0110x over previous
//
#include <hip/hip_runtime.h>
#include <stdint.h>

#define T_TOK 8192
#define DIMK 1024
#define NEXP 8
#define BM 128
#define BN 128
#define BK 64
#define MAXROWS (T_TOK + NEXP * BM)   /* 9216 gathered rows incl. padding */
#define MAXTILES (T_TOK / BM + NEXP)  /* 72 row tiles worst case */

typedef __attribute__((ext_vector_type(4))) float f32x4;
typedef __attribute__((ext_vector_type(8))) short short8;
typedef __attribute__((ext_vector_type(4))) unsigned short us4;

__device__ __forceinline__ unsigned short f2bf(float f) {
  uint32_t u = __builtin_bit_cast(uint32_t, f);
  u += 0x7FFFu + ((u >> 16) & 1u);   // RTNE
  return (unsigned short)(u >> 16);
}

__device__ __forceinline__ void gload_lds16(const void* g, void* l) {
  __builtin_amdgcn_global_load_lds(
      (const __attribute__((address_space(1))) void*)g,
      (__attribute__((address_space(3))) void*)l, 16, 0, 0);
}

// ---- init (replaces pathologically slow hipMemsetAsync fills) --------------
__global__ void k_init(int* __restrict__ hdr, int* __restrict__ row2tok) {
  int t = blockIdx.x * 256 + threadIdx.x;
  if (t < 64) hdr[t] = 0;
  if (t < MAXROWS) row2tok[t] = -1;
}

// ---- expert bucketing -------------------------------------------------------
__global__ void k_count(const int* __restrict__ idx, int* __restrict__ hdr) {
  int t = blockIdx.x * 256 + threadIdx.x;
  atomicAdd(&hdr[idx[t]], 1);
}

__global__ void k_offsets(int* hdr) {
  // hdr[0..7] = counts; hdr[8..15] = cursors (set to padded segment starts)
  if (threadIdx.x == 0) {
    int off = 0;
    for (int e = 0; e < NEXP; e++) {
      hdr[8 + e] = off;
      off += ((hdr[e] + BM - 1) >> 7) << 7;
    }
  }
}

__global__ void k_assign(const int* __restrict__ idx, int* __restrict__ hdr,
                         int* __restrict__ row2tok) {
  int t = blockIdx.x * 256 + threadIdx.x;
  int e = idx[t];
  int pos = atomicAdd(&hdr[8 + e], 1);
  row2tok[pos] = t;
}

// ---- dtype conversion / gather ---------------------------------------------
__global__ void k_wconv(const float* __restrict__ W, unsigned short* __restrict__ Wb) {
  int i = (blockIdx.x * 256 + threadIdx.x) * 4;
  f32x4 v = *(const f32x4*)(W + i);
  us4 o;
  o[0] = f2bf(v[0]); o[1] = f2bf(v[1]); o[2] = f2bf(v[2]); o[3] = f2bf(v[3]);
  *(us4*)(Wb + i) = o;
}

__global__ void k_gather(const float* __restrict__ X, const int* __restrict__ row2tok,
                         unsigned short* __restrict__ Xg) {
  int r = blockIdx.x;
  int t = row2tok[r];
  int d = threadIdx.x * 4;
  us4 o = {0, 0, 0, 0};
  if (t >= 0) {
    f32x4 v = *(const f32x4*)(X + (size_t)t * DIMK + d);
    o[0] = f2bf(v[0]); o[1] = f2bf(v[1]); o[2] = f2bf(v[2]); o[3] = f2bf(v[3]);
  }
  *(us4*)(Xg + (size_t)r * DIMK + d) = o;
}

// ---- grouped GEMM: C[row] = Xg[row] . Wb[e]^T ------------------------------
__global__ __launch_bounds__(256, 2) void k_gemm(
    const unsigned short* __restrict__ Xg, const unsigned short* __restrict__ Wb,
    const int* __restrict__ hdr, const int* __restrict__ row2tok,
    float* __restrict__ out) {
  __shared__ unsigned short A_lds[BM * BK];  // 16 KB
  __shared__ unsigned short B_lds[BN * BK];  // 16 KB

  // map blockIdx.x -> (expert, gathered row0) over padded segments
  int tile = blockIdx.x;
  int e = -1, row0 = 0, off = 0;
  for (int i = 0; i < NEXP; i++) {
    int te = (hdr[i] + BM - 1) >> 7;  // tiles for expert i
    if (e < 0) {
      if (tile < te) { e = i; row0 = off + tile * BM; }
      else tile -= te;
    }
    off += te << 7;
  }
  if (e < 0) return;

  const int tid = threadIdx.x;
  const int lane = tid & 63;
  const int wid = tid >> 6;
  const int wr = wid >> 1, wc = wid & 1;
  const int n0 = blockIdx.y * BN;

  // staging constants: lane covers 16B at LDS linear (chunk*1024 + lane*16)
  // LDS row = chunk*8 + (lane>>3); read side swizzles col by (row&7)<<4, so
  // the *source* column must carry the same XOR (both-sides-or-neither).
  const int st_r = lane >> 3;                        // row within 8-row chunk
  const int st_cb = ((lane & 7) ^ st_r) << 4;        // pre-swizzled byte col

  const char* a_base = (const char*)Xg + (size_t)row0 * (DIMK * 2);
  const char* b_base = (const char*)Wb + ((size_t)e * DIMK * DIMK + (size_t)n0 * DIMK) * 2;

  f32x4 acc[4][4];
  const f32x4 fzero = {0.f, 0.f, 0.f, 0.f};
#pragma unroll
  for (int m = 0; m < 4; m++)
#pragma unroll
    for (int n = 0; n < 4; n++) acc[m][n] = fzero;

  const int rsel = lane & 15;
  const int swz_r = (lane & 7) << 4;         // (row&7)<<4 for fragment rows
  const int kgrp = (lane >> 4) << 4;         // k-group byte offset (8 bf16)

  int a_row_b[4], b_row_b[4];
#pragma unroll
  for (int m = 0; m < 4; m++) a_row_b[m] = (wr * 64 + m * 16 + rsel) * (BK * 2);
#pragma unroll
  for (int n = 0; n < 4; n++) b_row_b[n] = (wc * 64 + n * 16 + rsel) * (BK * 2);

  for (int kt = 0; kt < DIMK / BK; kt++) {
    const int k0b = kt * BK * 2;
    // stage A (128x64) + B (128x64): 16 chunks of 1KB each, 4 per wave
#pragma unroll
    for (int j = 0; j < 4; j++) {
      int c = wid * 4 + j;
      int r = c * 8 + st_r;
      gload_lds16(a_base + (size_t)r * (DIMK * 2) + k0b + st_cb, (char*)A_lds + c * 1024);
      gload_lds16(b_base + (size_t)r * (DIMK * 2) + k0b + st_cb, (char*)B_lds + c * 1024);
    }
    __syncthreads();
#pragma unroll
    for (int ks = 0; ks < 2; ks++) {
      const int kb = ks * 64 + kgrp;
      short8 av[4], bv[4];
#pragma unroll
      for (int m = 0; m < 4; m++)
        av[m] = *(const short8*)((const char*)A_lds + a_row_b[m] + (kb ^ swz_r));
#pragma unroll
      for (int n = 0; n < 4; n++)
        bv[n] = *(const short8*)((const char*)B_lds + b_row_b[n] + (kb ^ swz_r));
#pragma unroll
      for (int m = 0; m < 4; m++)
#pragma unroll
        for (int n = 0; n < 4; n++)
          acc[m][n] = __builtin_amdgcn_mfma_f32_16x16x32_bf16(av[m], bv[n], acc[m][n], 0, 0, 0);
    }
    __syncthreads();
  }

  // epilogue: scatter rows back to tokens; pad rows have row2tok == -1
  const int rg4 = (lane >> 4) * 4;
#pragma unroll
  for (int m = 0; m < 4; m++) {
#pragma unroll
    for (int i = 0; i < 4; i++) {
      int rg = row0 + wr * 64 + m * 16 + rg4 + i;
      int tok = row2tok[rg];
      if (tok >= 0) {
        float* po = out + (size_t)tok * DIMK + n0 + wc * 64 + rsel;
#pragma unroll
        for (int n = 0; n < 4; n++) po[n * 16] = acc[m][n][i];
      }
    }
  }
}

extern "C" void kernel_launch(void* const* d_in, const int* in_sizes, int n_in,
                              void* d_out, int out_size, void* d_ws, size_t ws_size,
                              hipStream_t stream) {
  const float* X = (const float*)d_in[0];
  const float* W = (const float*)d_in[1];
  const int* idx = (const int*)d_in[2];
  float* out = (float*)d_out;
  char* ws = (char*)d_ws;

  int* hdr = (int*)ws;                                     // 64 ints
  int* row2tok = (int*)(ws + 256);                         // 9216 ints
  unsigned short* Wb = (unsigned short*)(ws + 65536);      // 16 MiB bf16 W
  unsigned short* Xg = (unsigned short*)(ws + 65536 + 16777216);  // 18 MiB bf16 gathered X

  k_init<<<(MAXROWS + 255) / 256, 256, 0, stream>>>(hdr, row2tok);
  k_count<<<T_TOK / 256, 256, 0, stream>>>(idx, hdr);
  k_offsets<<<1, 64, 0, stream>>>(hdr);
  k_assign<<<T_TOK / 256, 256, 0, stream>>>(idx, hdr, row2tok);
  k_wconv<<<(NEXP * DIMK * DIMK) / (256 * 4), 256, 0, stream>>>(W, Wb);
  k_gather<<<MAXROWS, 256, 0, stream>>>(X, row2tok, Xg);

  dim3 g(MAXTILES, DIMK / BN);
  k_gemm<<<g, 256, 0, stream>>>(Xg, Wb, hdr, row2tok, out);
}

// Round 3
// 70.299 us; speedup vs baseline: 1.8279x; 1.8081x over previous
//
#include <hip/hip_runtime.h>
#include <stdint.h>

#define T_TOK 8192
#define DIMK 1024
#define NEXP 8
#define BM 128
#define BN 128
#define BK 64
#define MAXROWS (T_TOK + NEXP * BM)   /* 9216 gathered rows incl. padding */
#define MAXTILES (T_TOK / BM + NEXP)  /* 72 row tiles worst case */

typedef __attribute__((ext_vector_type(4))) float f32x4;
typedef __attribute__((ext_vector_type(8))) short short8;
typedef __attribute__((ext_vector_type(4))) unsigned short us4;
typedef __attribute__((ext_vector_type(8))) unsigned short us8;

__device__ __forceinline__ unsigned short f2bf(float f) {
  uint32_t u = __builtin_bit_cast(uint32_t, f);
  u += 0x7FFFu + ((u >> 16) & 1u);   // RTNE
  return (unsigned short)(u >> 16);
}

__device__ __forceinline__ void gload_lds16(const void* g, void* l) {
  __builtin_amdgcn_global_load_lds(
      (const __attribute__((address_space(1))) void*)g,
      (__attribute__((address_space(3))) void*)l, 16, 0, 0);
}

// ---- prep: histogram + padded offsets + assignment + pad markers -----------
// Single block; replaces init/count/offsets/assign. 8192 tokens is tiny.
__global__ void k_prep(const int* __restrict__ idx, int* __restrict__ hdr,
                       int* __restrict__ row2tok) {
  __shared__ int h[NEXP];        // counts
  __shared__ int cur[NEXP];      // assignment cursors
  __shared__ int segs[NEXP + 1]; // padded segment starts
  const int tid = threadIdx.x;   // 256

  if (tid < NEXP) h[tid] = 0;
  __syncthreads();
  for (int i = tid; i < T_TOK; i += 256) atomicAdd(&h[idx[i]], 1);
  __syncthreads();
  if (tid == 0) {
    int off = 0;
    for (int e = 0; e < NEXP; e++) {
      segs[e] = off; cur[e] = off;
      hdr[e] = h[e]; hdr[8 + e] = off;
      off += ((h[e] + BM - 1) >> 7) << 7;
    }
    segs[NEXP] = off;
  }
  __syncthreads();
  // pad markers: tail of each segment, plus everything past the last segment
  for (int e = 0; e < NEXP; e++)
    for (int p = segs[e] + h[e] + tid; p < segs[e + 1]; p += 256) row2tok[p] = -1;
  for (int p = segs[NEXP] + tid; p < MAXROWS; p += 256) row2tok[p] = -1;
  // assignment (disjoint positions from the pads; no barrier needed)
  for (int i = tid; i < T_TOK; i += 256) {
    int e = idx[i];
    int pos = atomicAdd(&cur[e], 1);
    row2tok[pos] = i;
  }
}

// ---- fused W conversion + X gather (both fp32 -> bf16, 8 elems/thread) -----
// blocks [0, 4096): Wconv; blocks [4096, 8704): gather 2 rows/block.
__global__ void k_convgather(const float* __restrict__ W, const float* __restrict__ X,
                             const int* __restrict__ row2tok,
                             unsigned short* __restrict__ Wb,
                             unsigned short* __restrict__ Xg) {
  const int tid = threadIdx.x;
  const int b = blockIdx.x;
  const float* src;
  unsigned short* dst;
  if (b < 4096) {
    size_t base = (size_t)b * 2048 + tid * 8;
    src = W + base;
    dst = Wb + base;
  } else {
    int r = (b - 4096) * 2 + (tid >> 7);
    int t = row2tok[r];
    if (t < 0) return;  // pad row: leave as-is, its outputs are never stored
    int col = (tid & 127) * 8;
    src = X + (size_t)t * DIMK + col;
    dst = Xg + (size_t)r * DIMK + col;
  }
  f32x4 v0 = *(const f32x4*)src;
  f32x4 v1 = *(const f32x4*)(src + 4);
  us8 o;
  o[0] = f2bf(v0[0]); o[1] = f2bf(v0[1]); o[2] = f2bf(v0[2]); o[3] = f2bf(v0[3]);
  o[4] = f2bf(v1[0]); o[5] = f2bf(v1[1]); o[6] = f2bf(v1[2]); o[7] = f2bf(v1[3]);
  *(us8*)dst = o;
}

// ---- grouped GEMM: C[row] = Xg[row] . Wb[e]^T ------------------------------
__global__ __launch_bounds__(256, 2) void k_gemm(
    const unsigned short* __restrict__ Xg, const unsigned short* __restrict__ Wb,
    const int* __restrict__ hdr, const int* __restrict__ row2tok,
    float* __restrict__ out) {
  __shared__ unsigned short A_lds[BM * BK];  // 16 KB
  __shared__ unsigned short B_lds[BN * BK];  // 16 KB

  // map blockIdx.x -> (expert, gathered row0) over padded segments
  int tile = blockIdx.x;
  int e = -1, row0 = 0, off = 0;
  for (int i = 0; i < NEXP; i++) {
    int te = (hdr[i] + BM - 1) >> 7;  // tiles for expert i
    if (e < 0) {
      if (tile < te) { e = i; row0 = off + tile * BM; }
      else tile -= te;
    }
    off += te << 7;
  }
  if (e < 0) return;

  const int tid = threadIdx.x;
  const int lane = tid & 63;
  const int wid = tid >> 6;
  const int wr = wid >> 1, wc = wid & 1;
  const int n0 = blockIdx.y * BN;

  // staging: lane covers 16B at LDS linear (chunk*1024 + lane*16).
  // LDS row = chunk*8 + (lane>>3); read side swizzles col by (row&7)<<4, so
  // the *source* column carries the same XOR (both-sides-or-neither).
  const int st_r = lane >> 3;
  const int st_cb = ((lane & 7) ^ st_r) << 4;

  const char* a_base = (const char*)Xg + (size_t)row0 * (DIMK * 2);
  const char* b_base = (const char*)Wb + ((size_t)e * DIMK * DIMK + (size_t)n0 * DIMK) * 2;

  f32x4 acc[4][4];
  const f32x4 fzero = {0.f, 0.f, 0.f, 0.f};
#pragma unroll
  for (int m = 0; m < 4; m++)
#pragma unroll
    for (int n = 0; n < 4; n++) acc[m][n] = fzero;

  const int rsel = lane & 15;
  const int swz_r = (lane & 7) << 4;
  const int kgrp = (lane >> 4) << 4;

  int a_row_b[4], b_row_b[4];
#pragma unroll
  for (int m = 0; m < 4; m++) a_row_b[m] = (wr * 64 + m * 16 + rsel) * (BK * 2);
#pragma unroll
  for (int n = 0; n < 4; n++) b_row_b[n] = (wc * 64 + n * 16 + rsel) * (BK * 2);

  for (int kt = 0; kt < DIMK / BK; kt++) {
    const int k0b = kt * BK * 2;
#pragma unroll
    for (int j = 0; j < 4; j++) {
      int c = wid * 4 + j;
      int r = c * 8 + st_r;
      gload_lds16(a_base + (size_t)r * (DIMK * 2) + k0b + st_cb, (char*)A_lds + c * 1024);
      gload_lds16(b_base + (size_t)r * (DIMK * 2) + k0b + st_cb, (char*)B_lds + c * 1024);
    }
    __syncthreads();
#pragma unroll
    for (int ks = 0; ks < 2; ks++) {
      const int kb = ks * 64 + kgrp;
      short8 av[4], bv[4];
#pragma unroll
      for (int m = 0; m < 4; m++)
        av[m] = *(const short8*)((const char*)A_lds + a_row_b[m] + (kb ^ swz_r));
#pragma unroll
      for (int n = 0; n < 4; n++)
        bv[n] = *(const short8*)((const char*)B_lds + b_row_b[n] + (kb ^ swz_r));
#pragma unroll
      for (int m = 0; m < 4; m++)
#pragma unroll
        for (int n = 0; n < 4; n++)
          acc[m][n] = __builtin_amdgcn_mfma_f32_16x16x32_bf16(av[m], bv[n], acc[m][n], 0, 0, 0);
    }
    __syncthreads();
  }

  // epilogue: scatter rows back to tokens; pad rows have row2tok == -1
  const int rg4 = (lane >> 4) * 4;
#pragma unroll
  for (int m = 0; m < 4; m++) {
#pragma unroll
    for (int i = 0; i < 4; i++) {
      int rg = row0 + wr * 64 + m * 16 + rg4 + i;
      int tok = row2tok[rg];
      if (tok >= 0) {
        float* po = out + (size_t)tok * DIMK + n0 + wc * 64 + rsel;
#pragma unroll
        for (int n = 0; n < 4; n++) po[n * 16] = acc[m][n][i];
      }
    }
  }
}

extern "C" void kernel_launch(void* const* d_in, const int* in_sizes, int n_in,
                              void* d_out, int out_size, void* d_ws, size_t ws_size,
                              hipStream_t stream) {
  const float* X = (const float*)d_in[0];
  const float* W = (const float*)d_in[1];
  const int* idx = (const int*)d_in[2];
  float* out = (float*)d_out;
  char* ws = (char*)d_ws;

  int* hdr = (int*)ws;                                     // 64 ints
  int* row2tok = (int*)(ws + 256);                         // 9216 ints
  unsigned short* Wb = (unsigned short*)(ws + 65536);      // 16 MiB bf16 W
  unsigned short* Xg = (unsigned short*)(ws + 65536 + 16777216);  // 18 MiB bf16 gathered X

  k_prep<<<1, 256, 0, stream>>>(idx, hdr, row2tok);
  k_convgather<<<4096 + MAXROWS / 2, 256, 0, stream>>>(W, X, row2tok, Wb, Xg);

  dim3 g(MAXTILES, DIMK / BN);
  k_gemm<<<g, 256, 0, stream>>>(Xg, Wb, hdr, row2tok, out);
}